// Round 2
// baseline (1301.380 us; speedup 1.0000x reference)
//
#include <hip/hip_runtime.h>
#include <stdint.h>

// ---------- bf16 helpers (raw ushort representation) ----------
__device__ __forceinline__ float bf2f(unsigned short u) {
  union { unsigned int i; float f; } v; v.i = ((unsigned int)u) << 16; return v.f;
}
__device__ __forceinline__ unsigned short f2bf(float f) {
  union { float f; unsigned int i; } v; v.f = f;
  unsigned int i = v.i;
  unsigned int r = (i + 0x7fffu + ((i >> 16) & 1u)) >> 16;  // RNE
  return (unsigned short)r;
}

typedef __bf16 bf16x8 __attribute__((ext_vector_type(8)));
typedef float f32x4 __attribute__((ext_vector_type(4)));
union ABfrag { int4 i4; bf16x8 v; };

// ---------- dtype detection: are float inputs bf16-packed or float32? ----------
// For bf16 x[i]~N(0,1): low 16 bits of each 32-bit word are a valid bf16 with
// exponent in [100,140] (~always). For f32: low halves are mantissa bits
// (uniform) -> ~16% hit rate. Count over 1024 words, threshold 600.
__global__ __launch_bounds__(256) void k_detect(const unsigned int* __restrict__ x, int* flag) {
  __shared__ int cnt;
  if (threadIdx.x == 0) cnt = 0;
  __syncthreads();
  int c = 0;
  for (int i = threadIdx.x; i < 1024; i += 256) {
    unsigned int lo = x[i] & 0xFFFFu;
    int ex = (int)((lo >> 7) & 0xFF);
    if (ex >= 100 && ex <= 140) c++;
  }
  atomicAdd(&cnt, c);
  __syncthreads();
  if (threadIdx.x == 0) flag[0] = (cnt > 600) ? 1 : 0;  // 1 = bf16 inputs
}

// ---------- canonicalize small param tensors to f32 ----------
struct CanonDesc {
  const void* src[32];
  float* dst[32];
  int n[32];
  int cnt;
  int total;
};
__global__ __launch_bounds__(256) void k_canon(CanonDesc d, const int* __restrict__ flag) {
  int isbf = *flag;
  for (int idx = blockIdx.x * 256 + threadIdx.x; idx < d.total; idx += gridDim.x * 256) {
    int t = 0, off = idx;
    while (off >= d.n[t]) { off -= d.n[t]; ++t; }
    float v = isbf ? bf2f(((const unsigned short*)d.src[t])[off])
                   : ((const float*)d.src[t])[off];
    d.dst[t][off] = v;
  }
}

// ---------- x prep: raw -> f32 canon + bf16 copy ----------
__global__ __launch_bounds__(256) void k_xprep(const void* __restrict__ x, float* __restrict__ xc,
                                               unsigned short* __restrict__ xb, int n,
                                               const int* __restrict__ flag) {
  int i = blockIdx.x * 256 + threadIdx.x;
  if (i >= n) return;
  int isbf = *flag;
  float v = isbf ? bf2f(((const unsigned short*)x)[i]) : ((const float*)x)[i];
  xc[i] = v;
  xb[i] = f2bf(v);
}

// ---------- CSR build ----------
__global__ __launch_bounds__(256) void k_deg_init(int* degA, int* degB, int n) {
  int i = blockIdx.x * 256 + threadIdx.x;
  if (i < n) { degA[i] = 1; degB[i] = 1; }  // self loop
}
__global__ __launch_bounds__(256) void k_deg_count(const int* __restrict__ ei, int* degA, int* degB, int E) {
  int e = blockIdx.x * 256 + threadIdx.x;
  if (e < E) { atomicAdd(&degA[ei[E + e]], 1); atomicAdd(&degB[ei[e]], 1); }
}
__global__ __launch_bounds__(1024) void k_exscan(const int* __restrict__ deg, int* __restrict__ row, int n) {
  __shared__ int buf[1024];
  __shared__ int carry;
  if (threadIdx.x == 0) carry = 0;
  __syncthreads();
  int chunks = (n + 1023) / 1024;
  for (int c = 0; c < chunks; ++c) {
    int i = c * 1024 + threadIdx.x;
    int v = (i < n) ? deg[i] : 0;
    buf[threadIdx.x] = v;
    __syncthreads();
    for (int off = 1; off < 1024; off <<= 1) {
      int t = (threadIdx.x >= off) ? buf[threadIdx.x - off] : 0;
      __syncthreads();
      buf[threadIdx.x] += t;
      __syncthreads();
    }
    if (i < n) row[i] = carry + buf[threadIdx.x] - v;  // exclusive
    __syncthreads();
    if (threadIdx.x == 0) carry += buf[1023];
    __syncthreads();
  }
  if (threadIdx.x == 0) row[n] = carry;
}
__global__ __launch_bounds__(256) void k_selfloop(const int* __restrict__ rowA, const int* __restrict__ rowB,
                                                 int* colA, int* colB, int* curA, int* curB, int n) {
  int i = blockIdx.x * 256 + threadIdx.x;
  if (i < n) {
    int ra = rowA[i]; colA[ra] = i; curA[i] = ra + 1;
    int rb = rowB[i]; colB[rb] = i; curB[i] = rb + 1;
  }
}
__global__ __launch_bounds__(256) void k_scatter(const int* __restrict__ ei, int* colA, int* colB,
                                                 int* curA, int* curB, int E) {
  int e = blockIdx.x * 256 + threadIdx.x;
  if (e < E) {
    int s = ei[e], d = ei[E + e];
    colA[atomicAdd(&curA[d], 1)] = s;  // s2t: grouped by dst=ei[1], neighbor = src
    colB[atomicAdd(&curB[s], 1)] = d;  // t2s: grouped by dst=ei[0], neighbor = ei[1]
  }
}

// ---------- weight transpose [K][N] -> [N][K], raw dtype -> bf16 ----------
__global__ __launch_bounds__(256) void k_transpose(const void* __restrict__ W,
                                                   unsigned short* __restrict__ Wt, int K, int N,
                                                   const int* __restrict__ flag) {
  __shared__ unsigned short tile[32][33];
  int isbf = *flag;
  int nb = N >> 5;
  int bx = blockIdx.x % nb;   // n tile
  int by = blockIdx.x / nb;   // k tile
  int tx = threadIdx.x & 31;
  int ty = threadIdx.x >> 5;  // 0..7
  for (int r = ty; r < 32; r += 8) {
    size_t idx = (size_t)(by * 32 + r) * N + bx * 32 + tx;
    float v = isbf ? bf2f(((const unsigned short*)W)[idx]) : ((const float*)W)[idx];
    tile[r][tx] = f2bf(v);  // exact round-trip if already bf16
  }
  __syncthreads();
  for (int r = ty; r < 32; r += 8)
    Wt[(size_t)(bx * 32 + r) * K + by * 32 + tx] = tile[tx][r];
}

// ---------- bf16 MFMA matmul: C[M][N] = A[M][K] * Bt[N][K]^T, bf16 out ----------
// one wave = 16(M) x 64(N) tile; mfma_f32_16x16x32_bf16
__global__ __launch_bounds__(256) void k_mm_bf16(const unsigned short* __restrict__ A,
                                                 const unsigned short* __restrict__ Bt,
                                                 unsigned short* __restrict__ C,
                                                 int M, int N, int K) {
  int wg = blockIdx.x * 4 + (threadIdx.x >> 6);
  int ntiles = N >> 6;
  int tm = wg / ntiles, tn = wg % ntiles;
  int lane = threadIdx.x & 63;
  int mr = lane & 15, quad = lane >> 4;
  const unsigned short* arow = A + (size_t)(tm * 16 + mr) * K + quad * 8;
  const unsigned short* bbase = Bt + (size_t)(tn * 64 + mr) * K + quad * 8;
  f32x4 acc[4];
#pragma unroll
  for (int i = 0; i < 4; i++) acc[i] = (f32x4){0.f, 0.f, 0.f, 0.f};
  for (int k0 = 0; k0 < K; k0 += 32) {
    ABfrag a; a.i4 = *(const int4*)(arow + k0);
#pragma unroll
    for (int nt = 0; nt < 4; ++nt) {
      ABfrag b; b.i4 = *(const int4*)(bbase + (size_t)nt * 16 * K + k0);
      acc[nt] = __builtin_amdgcn_mfma_f32_16x16x32_bf16(a.v, b.v, acc[nt], 0, 0, 0);
    }
  }
#pragma unroll
  for (int nt = 0; nt < 4; ++nt)
#pragma unroll
    for (int r = 0; r < 4; ++r) {
      int row = tm * 16 + quad * 4 + r;       // C/D: row = quad*4+reg
      int col = tn * 64 + nt * 16 + mr;       //      col = lane&15
      C[(size_t)row * N + col] = f2bf(acc[nt][r]);
    }
}

// ---------- attention logits: es/ed[i][h] = sum_c h[i,h,c] * a_{s,d}[h,c] ----------
__global__ __launch_bounds__(256) void k_esed(const unsigned short* __restrict__ h,
                                              const float* __restrict__ a_s,
                                              const float* __restrict__ a_d,
                                              float* __restrict__ es, float* __restrict__ ed,
                                              int n, int C) {
  int idx = blockIdx.x * 256 + threadIdx.x;
  if (idx >= n * 32) return;
  int i = idx >> 5, hh = idx & 31;
  const unsigned short* hp = h + ((size_t)i * 32 + hh) * C;
  const float* sp = a_s + hh * C;
  const float* dp = a_d + hh * C;
  float e1 = 0.f, e2 = 0.f;
  for (int c = 0; c < C; ++c) {
    float hv = bf2f(hp[c]);
    e1 += hv * sp[c];
    e2 += hv * dp[c];
  }
  es[idx] = e1; ed[idx] = e2;
}

// ---------- GAT aggregation, C=64: block=node, wave=head-slice, lane=channel ----------
__global__ __launch_bounds__(256) void k_agg64(const unsigned short* __restrict__ h,
                                               const float* __restrict__ es, const float* __restrict__ ed,
                                               const int* __restrict__ rowp, const int* __restrict__ col,
                                               const float* __restrict__ bias,
                                               unsigned short* __restrict__ out, int n) {
  int i = blockIdx.x;
  int wid = threadIdx.x >> 6, lane = threadIdx.x & 63;
  __shared__ float red[4][64];
  int beg = rowp[i], end = rowp[i + 1];
  float acc = 0.f;
  for (int hh = wid; hh < 32; hh += 4) {
    float edv = ed[i * 32 + hh];
    float M = -1e30f;
    for (int j = beg; j < end; ++j) {
      float e = es[col[j] * 32 + hh] + edv;
      e = (e > 0.f) ? e : 0.2f * e;
      M = fmaxf(M, e);
    }
    float Z = 0.f, A = 0.f;
    for (int j = beg; j < end; ++j) {
      int s = col[j];
      float e = es[s * 32 + hh] + edv;
      e = (e > 0.f) ? e : 0.2f * e;
      float p = __expf(e - M);
      Z += p;
      A += p * bf2f(h[((size_t)s * 32 + hh) * 64 + lane]);
    }
    acc += A / Z;
  }
  red[wid][lane] = acc;
  __syncthreads();
  if (threadIdx.x < 64) {
    float v = red[0][threadIdx.x] + red[1][threadIdx.x] + red[2][threadIdx.x] + red[3][threadIdx.x];
    v = v * (1.f / 32.f) + bias[threadIdx.x];
    v = (v > 0.f) ? v : (__expf(v) - 1.f);  // elu
    out[(size_t)i * 64 + threadIdx.x] = f2bf(v);
  }
}

// ---------- GAT aggregation, C=16: writes final output (dtype per flag) ----------
__global__ __launch_bounds__(256) void k_agg16(const unsigned short* __restrict__ h,
                                               const float* __restrict__ es, const float* __restrict__ ed,
                                               const int* __restrict__ rowp, const int* __restrict__ col,
                                               const float* __restrict__ bias,
                                               void* __restrict__ outbase, size_t elem_off, int n,
                                               const int* __restrict__ flag) {
  int i = blockIdx.x;
  int wid = threadIdx.x >> 6, lane = threadIdx.x & 63;
  int hs = lane >> 4, c = lane & 15;
  __shared__ float red[4][16];
  int beg = rowp[i], end = rowp[i + 1];
  float acc = 0.f;
#pragma unroll
  for (int it = 0; it < 2; ++it) {
    int hh = it * 16 + wid * 4 + hs;
    float edv = ed[i * 32 + hh];
    float M = -1e30f;
    for (int j = beg; j < end; ++j) {
      float e = es[col[j] * 32 + hh] + edv;
      e = (e > 0.f) ? e : 0.2f * e;
      M = fmaxf(M, e);
    }
    float Z = 0.f, A = 0.f;
    for (int j = beg; j < end; ++j) {
      int s = col[j];
      float e = es[s * 32 + hh] + edv;
      e = (e > 0.f) ? e : 0.2f * e;
      float p = __expf(e - M);
      Z += p;
      A += p * bf2f(h[((size_t)s * 32 + hh) * 16 + c]);
    }
    acc += A / Z;
  }
  acc += __shfl_xor(acc, 16);
  acc += __shfl_xor(acc, 32);
  if (lane < 16) red[wid][c] = acc;
  __syncthreads();
  if (threadIdx.x < 16) {
    float v = red[0][threadIdx.x] + red[1][threadIdx.x] + red[2][threadIdx.x] + red[3][threadIdx.x];
    v = v * (1.f / 32.f) + bias[threadIdx.x];
    v = (v > 0.f) ? v : (__expf(v) - 1.f);
    size_t o = elem_off + (size_t)i * 16 + threadIdx.x;
    if (*flag) ((unsigned short*)outbase)[o] = f2bf(v);
    else       ((float*)outbase)[o] = v;
  }
}

// ---------- fused residual network: 16 nodes x 16 channels per block (f32) ----------
__global__ __launch_bounds__(256) void k_residual(const float* __restrict__ x,
    const float* __restrict__ rwa, const float* __restrict__ rba,
    const float* __restrict__ bn1g, const float* __restrict__ bn1b,
    const float* __restrict__ bn1m, const float* __restrict__ bn1v,
    const float* __restrict__ rwb, const float* __restrict__ rbb,
    const float* __restrict__ bn2g, const float* __restrict__ bn2b,
    const float* __restrict__ bn2m, const float* __restrict__ bn2v,
    const float* __restrict__ wsc, const float* __restrict__ bsc,
    const float* __restrict__ bnsg, const float* __restrict__ bnsb,
    const float* __restrict__ bnsm, const float* __restrict__ bnsv,
    const float* __restrict__ wfc, const float* __restrict__ bfc,
    void* __restrict__ outbase, size_t elem_off, int n, const int* __restrict__ flag) {
  __shared__ float xs[16][128];
  __shared__ float ha[16][16];
  __shared__ float tt[16][16];
  int nodebase = blockIdx.x * 16;
  for (int t = threadIdx.x; t < 16 * 128; t += 256)
    xs[t >> 7][t & 127] = x[(size_t)(nodebase + (t >> 7)) * 128 + (t & 127)];
  __syncthreads();
  int ni = threadIdx.x >> 4, c = threadIdx.x & 15;
  float ya = 0.f, ysc = 0.f;
  for (int k = 0; k < 128; ++k) {
    float xv = xs[ni][k];
    ya  += xv * rwa[k * 16 + c];
    ysc += xv * wsc[k * 16 + c];
  }
  ya += rba[c]; ysc += bsc[c];
  float s1 = bn1g[c] * rsqrtf(bn1v[c] + 1e-5f);
  ya = (ya - bn1m[c]) * s1 + bn1b[c];
  ya = fmaxf(ya, 0.f);
  float ss = bnsg[c] * rsqrtf(bnsv[c] + 1e-5f);
  ysc = (ysc - bnsm[c]) * ss + bnsb[c];
  ha[ni][c] = ya;
  __syncthreads();
  float h2 = rbb[c];
  for (int k = 0; k < 16; ++k) h2 += ha[ni][k] * rwb[k * 16 + c];
  float s2 = bn2g[c] * rsqrtf(bn2v[c] + 1e-5f);
  h2 = (h2 - bn2m[c]) * s2 + bn2b[c];
  tt[ni][c] = fmaxf(h2 + ysc, 0.f);
  __syncthreads();
  float o = bfc[c];
  for (int k = 0; k < 16; ++k) o += tt[ni][k] * wfc[k * 16 + c];
  size_t oo = elem_off + (size_t)(nodebase + ni) * 16 + c;
  if (*flag) ((unsigned short*)outbase)[oo] = f2bf(o);
  else       ((float*)outbase)[oo] = o;
}

extern "C" void kernel_launch(void* const* d_in, const int* in_sizes, int n_in,
                              void* d_out, int out_size, void* d_ws, size_t ws_size,
                              hipStream_t stream) {
  const int n = in_sizes[0] / 128;   // 10000
  const int E = in_sizes[1] / 2;     // 80000
  const int* ei = (const int*)d_in[1];

  char* wsp = (char*)d_ws; size_t off = 0;
  auto alloc = [&](size_t bytes) -> void* {
    void* p = wsp + off; off = (off + bytes + 255) & ~(size_t)255; return p;
  };
  int* flag = (int*)alloc(4);
  float* xc = (float*)alloc((size_t)n * 128 * 4);
  unsigned short* xb = (unsigned short*)alloc((size_t)n * 128 * 2);
  unsigned short* W1t = (unsigned short*)alloc((size_t)2048 * 128 * 2);
  unsigned short* W2t = (unsigned short*)alloc((size_t)512 * 64 * 2);
  unsigned short* W3t = (unsigned short*)alloc((size_t)2048 * 128 * 2);
  unsigned short* W4t = (unsigned short*)alloc((size_t)512 * 64 * 2);
  unsigned short* hbuf = (unsigned short*)alloc((size_t)n * 2048 * 2);
  unsigned short* hbuf2 = hbuf;  // reuse (lifetimes disjoint)
  float* es = (float*)alloc((size_t)n * 32 * 4);
  float* ed = (float*)alloc((size_t)n * 32 * 4);
  unsigned short* xsbuf = (unsigned short*)alloc((size_t)n * 64 * 2);
  unsigned short* xtbuf = (unsigned short*)alloc((size_t)n * 64 * 2);
  int* rowA = (int*)alloc((size_t)(n + 1) * 4);
  int* rowB = (int*)alloc((size_t)(n + 1) * 4);
  int* colA = (int*)alloc((size_t)(E + n) * 4);
  int* colB = (int*)alloc((size_t)(E + n) * 4);
  int* degA = (int*)alloc((size_t)n * 4);
  int* degB = (int*)alloc((size_t)n * 4);
  int* curA = (int*)alloc((size_t)n * 4);
  int* curB = (int*)alloc((size_t)n * 4);

  // canonical f32 copies of the 32 small param tensors (indices 3..37 minus W's)
  static const int cidx[32] = {3,4,5, 7,8,9, 11,12,13, 15,16,17,
                               18,19,20,21,22,23,24,25,26,27,28,29,
                               30,31,32,33,34,35,36,37};
  CanonDesc cd; cd.cnt = 32; cd.total = 0;
  float* canon[38] = {nullptr};
  for (int t = 0; t < 32; ++t) {
    int ii = cidx[t];
    canon[ii] = (float*)alloc((size_t)in_sizes[ii] * 4);
    cd.src[t] = d_in[ii];
    cd.dst[t] = canon[ii];
    cd.n[t] = in_sizes[ii];
    cd.total += in_sizes[ii];
  }
  (void)ws_size; (void)n_in; (void)out_size;

  // ---- dtype detect + canonicalize ----
  k_detect<<<1, 256, 0, stream>>>((const unsigned int*)d_in[0], flag);
  k_canon<<<64, 256, 0, stream>>>(cd, flag);
  k_xprep<<<(n * 128 + 255) / 256, 256, 0, stream>>>(d_in[0], xc, xb, n * 128, flag);

  // ---- CSR build (both flows) ----
  k_deg_init<<<(n + 255) / 256, 256, 0, stream>>>(degA, degB, n);
  k_deg_count<<<(E + 255) / 256, 256, 0, stream>>>(ei, degA, degB, E);
  k_exscan<<<1, 1024, 0, stream>>>(degA, rowA, n);
  k_exscan<<<1, 1024, 0, stream>>>(degB, rowB, n);
  k_selfloop<<<(n + 255) / 256, 256, 0, stream>>>(rowA, rowB, colA, colB, curA, curB, n);
  k_scatter<<<(E + 255) / 256, 256, 0, stream>>>(ei, colA, colB, curA, curB, E);

  // ---- weight transposes (raw -> bf16 [N][K]) ----
  k_transpose<<<(2048 / 32) * (128 / 32), 256, 0, stream>>>(d_in[2],  W1t, 128, 2048, flag);
  k_transpose<<<(512 / 32) * (64 / 32),  256, 0, stream>>>(d_in[6],  W2t, 64, 512, flag);
  k_transpose<<<(2048 / 32) * (128 / 32), 256, 0, stream>>>(d_in[10], W3t, 128, 2048, flag);
  k_transpose<<<(512 / 32) * (64 / 32),  256, 0, stream>>>(d_in[14], W4t, 64, 512, flag);

  const int mt = n / 16;  // 625
  // ---- Layer 1 (s2t, C=64): x_s = elu(gat1(x)) ----
  k_mm_bf16<<<mt * (2048 / 64) / 4, 256, 0, stream>>>(xb, W1t, hbuf, n, 2048, 128);
  k_esed<<<(n * 32) / 256, 256, 0, stream>>>(hbuf, canon[3], canon[4], es, ed, n, 64);
  k_agg64<<<n, 256, 0, stream>>>(hbuf, es, ed, rowA, colA, canon[5], xsbuf, n);
  // ---- Layer 2 (s2t, C=16): x_in -> out[0] ----
  k_mm_bf16<<<mt * (512 / 64) / 4, 256, 0, stream>>>(xsbuf, W2t, hbuf2, n, 512, 64);
  k_esed<<<(n * 32) / 256, 256, 0, stream>>>(hbuf2, canon[7], canon[8], es, ed, n, 16);
  k_agg16<<<n, 256, 0, stream>>>(hbuf2, es, ed, rowA, colA, canon[9], d_out, 0, n, flag);
  // ---- Layer 3 (t2s, C=64): x_t = elu(gat3(x)) ----
  k_mm_bf16<<<mt * (2048 / 64) / 4, 256, 0, stream>>>(xb, W3t, hbuf, n, 2048, 128);
  k_esed<<<(n * 32) / 256, 256, 0, stream>>>(hbuf, canon[11], canon[12], es, ed, n, 64);
  k_agg64<<<n, 256, 0, stream>>>(hbuf, es, ed, rowB, colB, canon[13], xtbuf, n);
  // ---- Layer 4 (t2s, C=16): x_out -> out[1] ----
  k_mm_bf16<<<mt * (512 / 64) / 4, 256, 0, stream>>>(xtbuf, W4t, hbuf2, n, 512, 64);
  k_esed<<<(n * 32) / 256, 256, 0, stream>>>(hbuf2, canon[15], canon[16], es, ed, n, 16);
  k_agg16<<<n, 256, 0, stream>>>(hbuf2, es, ed, rowB, colB, canon[17], d_out, (size_t)n * 16, n, flag);
  // ---- Residual MLP: x_self -> out[2] ----
  k_residual<<<n / 16, 256, 0, stream>>>(xc,
      canon[18], canon[19], canon[20], canon[21], canon[22], canon[23],
      canon[24], canon[25], canon[26], canon[27], canon[28], canon[29],
      canon[30], canon[31], canon[32], canon[33], canon[34], canon[35],
      canon[36], canon[37],
      d_out, (size_t)2 * n * 16, n, flag);
}

// Round 3
// 576.498 us; speedup vs baseline: 2.2574x; 2.2574x over previous
//
#include <hip/hip_runtime.h>
#include <stdint.h>

// ---------- bf16 helpers (raw ushort representation) ----------
__device__ __forceinline__ float bf2f(unsigned short u) {
  union { unsigned int i; float f; } v; v.i = ((unsigned int)u) << 16; return v.f;
}
__device__ __forceinline__ unsigned short f2bf(float f) {
  union { float f; unsigned int i; } v; v.f = f;
  unsigned int i = v.i;
  unsigned int r = (i + 0x7fffu + ((i >> 16) & 1u)) >> 16;  // RNE
  return (unsigned short)r;
}

typedef __bf16 bf16x8 __attribute__((ext_vector_type(8)));
typedef float f32x4 __attribute__((ext_vector_type(4)));
union ABfrag { int4 i4; bf16x8 v; };

// ---------- dtype detection (bf16-packed vs f32 inputs) ----------
__global__ __launch_bounds__(256) void k_detect(const unsigned int* __restrict__ x, int* flag) {
  __shared__ int cnt;
  if (threadIdx.x == 0) cnt = 0;
  __syncthreads();
  int c = 0;
  for (int i = threadIdx.x; i < 1024; i += 256) {
    unsigned int lo = x[i] & 0xFFFFu;
    int ex = (int)((lo >> 7) & 0xFF);
    if (ex >= 100 && ex <= 140) c++;
  }
  atomicAdd(&cnt, c);
  __syncthreads();
  if (threadIdx.x == 0) flag[0] = (cnt > 600) ? 1 : 0;  // 1 = bf16 inputs
}

// ---------- canonicalize small param tensors to f32 ----------
struct CanonDesc {
  const void* src[32];
  float* dst[32];
  int n[32];
  int cnt;
  int total;
};
__global__ __launch_bounds__(256) void k_canon(CanonDesc d, const int* __restrict__ flag) {
  int isbf = *flag;
  for (int idx = blockIdx.x * 256 + threadIdx.x; idx < d.total; idx += gridDim.x * 256) {
    int t = 0, off = idx;
    while (off >= d.n[t]) { off -= d.n[t]; ++t; }
    float v = isbf ? bf2f(((const unsigned short*)d.src[t])[off])
                   : ((const float*)d.src[t])[off];
    d.dst[t][off] = v;
  }
}

// ---------- x prep: raw -> f32 canon + bf16 copy ----------
__global__ __launch_bounds__(256) void k_xprep(const void* __restrict__ x, float* __restrict__ xc,
                                               unsigned short* __restrict__ xb, int n,
                                               const int* __restrict__ flag) {
  int i = blockIdx.x * 256 + threadIdx.x;
  if (i >= n) return;
  int isbf = *flag;
  float v = isbf ? bf2f(((const unsigned short*)x)[i]) : ((const float*)x)[i];
  xc[i] = v;
  xb[i] = f2bf(v);
}

// ---------- CSR build ----------
__global__ __launch_bounds__(256) void k_deg_init(int* degA, int* degB, int n) {
  int i = blockIdx.x * 256 + threadIdx.x;
  if (i < n) { degA[i] = 1; degB[i] = 1; }  // self loop
}
__global__ __launch_bounds__(256) void k_deg_count(const int* __restrict__ ei, int* degA, int* degB, int E) {
  int e = blockIdx.x * 256 + threadIdx.x;
  if (e < E) { atomicAdd(&degA[ei[E + e]], 1); atomicAdd(&degB[ei[e]], 1); }
}
__global__ __launch_bounds__(1024) void k_exscan(const int* __restrict__ deg, int* __restrict__ row, int n) {
  __shared__ int buf[1024];
  __shared__ int carry;
  if (threadIdx.x == 0) carry = 0;
  __syncthreads();
  int chunks = (n + 1023) / 1024;
  for (int c = 0; c < chunks; ++c) {
    int i = c * 1024 + threadIdx.x;
    int v = (i < n) ? deg[i] : 0;
    buf[threadIdx.x] = v;
    __syncthreads();
    for (int off = 1; off < 1024; off <<= 1) {
      int t = (threadIdx.x >= off) ? buf[threadIdx.x - off] : 0;
      __syncthreads();
      buf[threadIdx.x] += t;
      __syncthreads();
    }
    if (i < n) row[i] = carry + buf[threadIdx.x] - v;  // exclusive
    __syncthreads();
    if (threadIdx.x == 0) carry += buf[1023];
    __syncthreads();
  }
  if (threadIdx.x == 0) row[n] = carry;
}
__global__ __launch_bounds__(256) void k_selfloop(const int* __restrict__ rowA, const int* __restrict__ rowB,
                                                 int* colA, int* colB, int* curA, int* curB, int n) {
  int i = blockIdx.x * 256 + threadIdx.x;
  if (i < n) {
    int ra = rowA[i]; colA[ra] = i; curA[i] = ra + 1;
    int rb = rowB[i]; colB[rb] = i; curB[i] = rb + 1;
  }
}
__global__ __launch_bounds__(256) void k_scatter(const int* __restrict__ ei, int* colA, int* colB,
                                                 int* curA, int* curB, int E) {
  int e = blockIdx.x * 256 + threadIdx.x;
  if (e < E) {
    int s = ei[e], d = ei[E + e];
    colA[atomicAdd(&curA[d], 1)] = s;
    colB[atomicAdd(&curB[s], 1)] = d;
  }
}

// ---------- weight transpose [K][N] -> [N][K], raw dtype -> bf16 ----------
__global__ __launch_bounds__(256) void k_transpose(const void* __restrict__ W,
                                                   unsigned short* __restrict__ Wt, int K, int N,
                                                   const int* __restrict__ flag) {
  __shared__ unsigned short tile[32][33];
  int isbf = *flag;
  int nb = N >> 5;
  int bx = blockIdx.x % nb;
  int by = blockIdx.x / nb;
  int tx = threadIdx.x & 31;
  int ty = threadIdx.x >> 5;
  for (int r = ty; r < 32; r += 8) {
    size_t idx = (size_t)(by * 32 + r) * N + bx * 32 + tx;
    float v = isbf ? bf2f(((const unsigned short*)W)[idx]) : ((const float*)W)[idx];
    tile[r][tx] = f2bf(v);
  }
  __syncthreads();
  for (int r = ty; r < 32; r += 8)
    Wt[(size_t)(bx * 32 + r) * K + by * 32 + tx] = tile[tx][r];
}

// ---------- bf16 MFMA matmul + fused es/ed epilogue ----------
// C[M][N] = A[M][K] * Bt[N][K]^T; also es/ed[row][head] = sum_c h*a
// CH = per-head channels (64 or 16)
template<int CH>
__global__ __launch_bounds__(256) void k_mm_es(const unsigned short* __restrict__ A,
                                               const unsigned short* __restrict__ Bt,
                                               unsigned short* __restrict__ C,
                                               const float* __restrict__ a_s,
                                               const float* __restrict__ a_d,
                                               float* __restrict__ es, float* __restrict__ ed,
                                               int M, int N, int K) {
  int wg = blockIdx.x * 4 + (threadIdx.x >> 6);
  int ntiles = N >> 6;
  int tm = wg / ntiles, tn = wg % ntiles;
  int lane = threadIdx.x & 63;
  int mr = lane & 15, quad = lane >> 4;
  const unsigned short* arow = A + (size_t)(tm * 16 + mr) * K + quad * 8;
  const unsigned short* bbase = Bt + (size_t)(tn * 64 + mr) * K + quad * 8;
  f32x4 acc[4];
#pragma unroll
  for (int i = 0; i < 4; i++) acc[i] = (f32x4){0.f, 0.f, 0.f, 0.f};
  for (int k0 = 0; k0 < K; k0 += 32) {
    ABfrag a; a.i4 = *(const int4*)(arow + k0);
#pragma unroll
    for (int nt = 0; nt < 4; ++nt) {
      ABfrag b; b.i4 = *(const int4*)(bbase + (size_t)nt * 16 * K + k0);
      acc[nt] = __builtin_amdgcn_mfma_f32_16x16x32_bf16(a.v, b.v, acc[nt], 0, 0, 0);
    }
  }
#pragma unroll
  for (int nt = 0; nt < 4; ++nt)
#pragma unroll
    for (int r = 0; r < 4; ++r) {
      int row = tm * 16 + quad * 4 + r;
      int col = tn * 64 + nt * 16 + mr;
      C[(size_t)row * N + col] = f2bf(acc[nt][r]);
    }
  // ---- fused attention-logit epilogue ----
  if (CH == 64) {
    // head = tn; c = nt*16+mr
    float pes[4] = {0.f,0.f,0.f,0.f}, ped[4] = {0.f,0.f,0.f,0.f};
    const float* asr = a_s + tn * 64;
    const float* adr = a_d + tn * 64;
#pragma unroll
    for (int nt = 0; nt < 4; ++nt) {
      float ws = asr[nt * 16 + mr], wd = adr[nt * 16 + mr];
#pragma unroll
      for (int r = 0; r < 4; ++r) { pes[r] += acc[nt][r] * ws; ped[r] += acc[nt][r] * wd; }
    }
#pragma unroll
    for (int m = 1; m < 16; m <<= 1)
#pragma unroll
      for (int r = 0; r < 4; ++r) {
        pes[r] += __shfl_xor(pes[r], m);
        ped[r] += __shfl_xor(ped[r], m);
      }
    if (mr == 0) {
#pragma unroll
      for (int r = 0; r < 4; ++r) {
        int row = tm * 16 + quad * 4 + r;
        es[row * 32 + tn] = pes[r];
        ed[row * 32 + tn] = ped[r];
      }
    }
  } else {
    // CH==16: head = tn*4+nt; c = mr
    float pes[4][4], ped[4][4];
#pragma unroll
    for (int nt = 0; nt < 4; ++nt) {
      float ws = a_s[(tn * 4 + nt) * 16 + mr];
      float wd = a_d[(tn * 4 + nt) * 16 + mr];
#pragma unroll
      for (int r = 0; r < 4; ++r) { pes[nt][r] = acc[nt][r] * ws; ped[nt][r] = acc[nt][r] * wd; }
    }
#pragma unroll
    for (int m = 1; m < 16; m <<= 1)
#pragma unroll
      for (int nt = 0; nt < 4; ++nt)
#pragma unroll
        for (int r = 0; r < 4; ++r) {
          pes[nt][r] += __shfl_xor(pes[nt][r], m);
          ped[nt][r] += __shfl_xor(ped[nt][r], m);
        }
    if (mr == 0) {
#pragma unroll
      for (int nt = 0; nt < 4; ++nt)
#pragma unroll
        for (int r = 0; r < 4; ++r) {
          int row = tm * 16 + quad * 4 + r;
          es[row * 32 + tn * 4 + nt] = pes[nt][r];
          ed[row * 32 + tn * 4 + nt] = ped[nt][r];
        }
    }
  }
}

// ---------- softmax M/Z + p per CSR slot: wave per node ----------
__global__ __launch_bounds__(256) void k_mz(const float* __restrict__ es, const float* __restrict__ ed,
                                            const int* __restrict__ rowp, const int* __restrict__ col,
                                            float* __restrict__ p, float* __restrict__ zinv, int n) {
  int wid = threadIdx.x >> 6, lane = threadIdx.x & 63;
  int i = blockIdx.x * 4 + wid;
  if (i >= n) return;
  int j2 = lane >> 5, h = lane & 31;
  int beg = rowp[i], end = rowp[i + 1];
  float edv = ed[i * 32 + h];
  float M = -1e30f;
  for (int j = beg + j2; j < end; j += 2) {
    float e = es[col[j] * 32 + h] + edv;
    e = (e > 0.f) ? e : 0.2f * e;
    M = fmaxf(M, e);
  }
  M = fmaxf(M, __shfl_xor(M, 32));
  float Z = 0.f;
  for (int j = beg + j2; j < end; j += 2) {
    float e = es[col[j] * 32 + h] + edv;
    e = (e > 0.f) ? e : 0.2f * e;
    float pj = __expf(e - M);
    p[(size_t)j * 32 + h] = pj;
    Z += pj;
  }
  Z += __shfl_xor(Z, 32);
  if (lane < 32) zinv[i * 32 + h] = 1.0f / Z;
}

// ---------- one-pass weighted gather, C=64 ----------
__global__ __launch_bounds__(256) void k_gather64(const unsigned short* __restrict__ h,
                                                  const float* __restrict__ p,
                                                  const float* __restrict__ zinv,
                                                  const int* __restrict__ rowp, const int* __restrict__ col,
                                                  const float* __restrict__ bias,
                                                  unsigned short* __restrict__ out, int n) {
  int i = blockIdx.x;
  int wid = threadIdx.x >> 6, lane = threadIdx.x & 63;
  __shared__ float red[4][64];
  int beg = rowp[i], end = rowp[i + 1];
  int hbase = wid * 8;
  float acc[8] = {0.f,0.f,0.f,0.f,0.f,0.f,0.f,0.f};
  for (int j = beg; j < end; ++j) {
    int s = col[j];
    const unsigned short* hp = h + (size_t)s * 2048 + hbase * 64 + lane;
    const float* pp = p + (size_t)j * 32 + hbase;
#pragma unroll
    for (int q = 0; q < 8; ++q)
      acc[q] += pp[q] * bf2f(hp[q * 64]);
  }
  float v = 0.f;
  const float* zi = zinv + i * 32 + hbase;
#pragma unroll
  for (int q = 0; q < 8; ++q) v += acc[q] * zi[q];
  red[wid][lane] = v;
  __syncthreads();
  if (threadIdx.x < 64) {
    float t = red[0][threadIdx.x] + red[1][threadIdx.x] + red[2][threadIdx.x] + red[3][threadIdx.x];
    t = t * (1.f / 32.f) + bias[threadIdx.x];
    t = (t > 0.f) ? t : (__expf(t) - 1.f);  // elu
    out[(size_t)i * 64 + threadIdx.x] = f2bf(t);
  }
}

// ---------- one-pass weighted gather, C=16 (writes final output) ----------
__global__ __launch_bounds__(256) void k_gather16(const unsigned short* __restrict__ h,
                                                  const float* __restrict__ p,
                                                  const float* __restrict__ zinv,
                                                  const int* __restrict__ rowp, const int* __restrict__ col,
                                                  const float* __restrict__ bias,
                                                  void* __restrict__ outbase, size_t elem_off, int n,
                                                  const int* __restrict__ flag) {
  int i = blockIdx.x;
  int wid = threadIdx.x >> 6, lane = threadIdx.x & 63;
  int hq = lane >> 4, c = lane & 15;
  __shared__ float red[4][16];
  int beg = rowp[i], end = rowp[i + 1];
  float acc[2] = {0.f, 0.f};
  for (int j = beg; j < end; ++j) {
    int s = col[j];
    const unsigned short* hp = h + (size_t)s * 512;
    const float* pp = p + (size_t)j * 32;
#pragma unroll
    for (int q = 0; q < 2; ++q) {
      int hh = wid * 8 + q * 4 + hq;
      acc[q] += pp[hh] * bf2f(hp[hh * 16 + c]);
    }
  }
  float v = acc[0] * zinv[i * 32 + wid * 8 + hq] + acc[1] * zinv[i * 32 + wid * 8 + 4 + hq];
  v += __shfl_xor(v, 16);
  v += __shfl_xor(v, 32);
  if (lane < 16) red[wid][c] = v;
  __syncthreads();
  if (threadIdx.x < 16) {
    float t = red[0][threadIdx.x] + red[1][threadIdx.x] + red[2][threadIdx.x] + red[3][threadIdx.x];
    t = t * (1.f / 32.f) + bias[threadIdx.x];
    t = (t > 0.f) ? t : (__expf(t) - 1.f);
    size_t o = elem_off + (size_t)i * 16 + threadIdx.x;
    if (*flag) ((unsigned short*)outbase)[o] = f2bf(t);
    else       ((float*)outbase)[o] = t;
  }
}

// ---------- fused residual network (f32) ----------
__global__ __launch_bounds__(256) void k_residual(const float* __restrict__ x,
    const float* __restrict__ rwa, const float* __restrict__ rba,
    const float* __restrict__ bn1g, const float* __restrict__ bn1b,
    const float* __restrict__ bn1m, const float* __restrict__ bn1v,
    const float* __restrict__ rwb, const float* __restrict__ rbb,
    const float* __restrict__ bn2g, const float* __restrict__ bn2b,
    const float* __restrict__ bn2m, const float* __restrict__ bn2v,
    const float* __restrict__ wsc, const float* __restrict__ bsc,
    const float* __restrict__ bnsg, const float* __restrict__ bnsb,
    const float* __restrict__ bnsm, const float* __restrict__ bnsv,
    const float* __restrict__ wfc, const float* __restrict__ bfc,
    void* __restrict__ outbase, size_t elem_off, int n, const int* __restrict__ flag) {
  __shared__ float xs[16][128];
  __shared__ float ha[16][16];
  __shared__ float tt[16][16];
  int nodebase = blockIdx.x * 16;
  for (int t = threadIdx.x; t < 16 * 128; t += 256)
    xs[t >> 7][t & 127] = x[(size_t)(nodebase + (t >> 7)) * 128 + (t & 127)];
  __syncthreads();
  int ni = threadIdx.x >> 4, c = threadIdx.x & 15;
  float ya = 0.f, ysc = 0.f;
  for (int k = 0; k < 128; ++k) {
    float xv = xs[ni][k];
    ya  += xv * rwa[k * 16 + c];
    ysc += xv * wsc[k * 16 + c];
  }
  ya += rba[c]; ysc += bsc[c];
  float s1 = bn1g[c] * rsqrtf(bn1v[c] + 1e-5f);
  ya = (ya - bn1m[c]) * s1 + bn1b[c];
  ya = fmaxf(ya, 0.f);
  float ss = bnsg[c] * rsqrtf(bnsv[c] + 1e-5f);
  ysc = (ysc - bnsm[c]) * ss + bnsb[c];
  ha[ni][c] = ya;
  __syncthreads();
  float h2 = rbb[c];
  for (int k = 0; k < 16; ++k) h2 += ha[ni][k] * rwb[k * 16 + c];
  float s2 = bn2g[c] * rsqrtf(bn2v[c] + 1e-5f);
  h2 = (h2 - bn2m[c]) * s2 + bn2b[c];
  tt[ni][c] = fmaxf(h2 + ysc, 0.f);
  __syncthreads();
  float o = bfc[c];
  for (int k = 0; k < 16; ++k) o += tt[ni][k] * wfc[k * 16 + c];
  size_t oo = elem_off + (size_t)(nodebase + ni) * 16 + c;
  if (*flag) ((unsigned short*)outbase)[oo] = f2bf(o);
  else       ((float*)outbase)[oo] = o;
}

extern "C" void kernel_launch(void* const* d_in, const int* in_sizes, int n_in,
                              void* d_out, int out_size, void* d_ws, size_t ws_size,
                              hipStream_t stream) {
  const int n = in_sizes[0] / 128;   // 10000
  const int E = in_sizes[1] / 2;     // 80000
  const int* ei = (const int*)d_in[1];

  char* wsp = (char*)d_ws; size_t off = 0;
  auto alloc = [&](size_t bytes) -> void* {
    void* p = wsp + off; off = (off + bytes + 255) & ~(size_t)255; return p;
  };
  int* flag = (int*)alloc(4);
  float* xc = (float*)alloc((size_t)n * 128 * 4);
  unsigned short* xb = (unsigned short*)alloc((size_t)n * 128 * 2);
  unsigned short* W1t = (unsigned short*)alloc((size_t)2048 * 128 * 2);
  unsigned short* W2t = (unsigned short*)alloc((size_t)512 * 64 * 2);
  unsigned short* W3t = (unsigned short*)alloc((size_t)2048 * 128 * 2);
  unsigned short* W4t = (unsigned short*)alloc((size_t)512 * 64 * 2);
  unsigned short* hbuf = (unsigned short*)alloc((size_t)n * 2048 * 2);
  unsigned short* hbuf2 = hbuf;  // reuse (lifetimes disjoint)
  float* es = (float*)alloc((size_t)n * 32 * 4);
  float* ed = (float*)alloc((size_t)n * 32 * 4);
  float* pbuf = (float*)alloc((size_t)(E + n) * 32 * 4);
  float* zinv = (float*)alloc((size_t)n * 32 * 4);
  unsigned short* xsbuf = (unsigned short*)alloc((size_t)n * 64 * 2);
  unsigned short* xtbuf = (unsigned short*)alloc((size_t)n * 64 * 2);
  int* rowA = (int*)alloc((size_t)(n + 1) * 4);
  int* rowB = (int*)alloc((size_t)(n + 1) * 4);
  int* colA = (int*)alloc((size_t)(E + n) * 4);
  int* colB = (int*)alloc((size_t)(E + n) * 4);
  int* degA = (int*)alloc((size_t)n * 4);
  int* degB = (int*)alloc((size_t)n * 4);
  int* curA = (int*)alloc((size_t)n * 4);
  int* curB = (int*)alloc((size_t)n * 4);

  static const int cidx[32] = {3,4,5, 7,8,9, 11,12,13, 15,16,17,
                               18,19,20,21,22,23,24,25,26,27,28,29,
                               30,31,32,33,34,35,36,37};
  CanonDesc cd; cd.cnt = 32; cd.total = 0;
  float* canon[38] = {nullptr};
  for (int t = 0; t < 32; ++t) {
    int ii = cidx[t];
    canon[ii] = (float*)alloc((size_t)in_sizes[ii] * 4);
    cd.src[t] = d_in[ii];
    cd.dst[t] = canon[ii];
    cd.n[t] = in_sizes[ii];
    cd.total += in_sizes[ii];
  }
  (void)ws_size; (void)n_in; (void)out_size;

  // ---- dtype detect + canonicalize ----
  k_detect<<<1, 256, 0, stream>>>((const unsigned int*)d_in[0], flag);
  k_canon<<<64, 256, 0, stream>>>(cd, flag);
  k_xprep<<<(n * 128 + 255) / 256, 256, 0, stream>>>(d_in[0], xc, xb, n * 128, flag);

  // ---- CSR build (both flows) ----
  k_deg_init<<<(n + 255) / 256, 256, 0, stream>>>(degA, degB, n);
  k_deg_count<<<(E + 255) / 256, 256, 0, stream>>>(ei, degA, degB, E);
  k_exscan<<<1, 1024, 0, stream>>>(degA, rowA, n);
  k_exscan<<<1, 1024, 0, stream>>>(degB, rowB, n);
  k_selfloop<<<(n + 255) / 256, 256, 0, stream>>>(rowA, rowB, colA, colB, curA, curB, n);
  k_scatter<<<(E + 255) / 256, 256, 0, stream>>>(ei, colA, colB, curA, curB, E);

  // ---- weight transposes (raw -> bf16 [N][K]) ----
  k_transpose<<<(2048 / 32) * (128 / 32), 256, 0, stream>>>(d_in[2],  W1t, 128, 2048, flag);
  k_transpose<<<(512 / 32) * (64 / 32),  256, 0, stream>>>(d_in[6],  W2t, 64, 512, flag);
  k_transpose<<<(2048 / 32) * (128 / 32), 256, 0, stream>>>(d_in[10], W3t, 128, 2048, flag);
  k_transpose<<<(512 / 32) * (64 / 32),  256, 0, stream>>>(d_in[14], W4t, 64, 512, flag);

  const int mt = n / 16;  // 625
  // ---- Layer 1 (s2t, C=64): x_s ----
  k_mm_es<64><<<mt * 32 / 4, 256, 0, stream>>>(xb, W1t, hbuf, canon[3], canon[4], es, ed, n, 2048, 128);
  k_mz<<<(n + 3) / 4, 256, 0, stream>>>(es, ed, rowA, colA, pbuf, zinv, n);
  k_gather64<<<n, 256, 0, stream>>>(hbuf, pbuf, zinv, rowA, colA, canon[5], xsbuf, n);
  // ---- Layer 2 (s2t, C=16): x_in -> out[0] ----
  k_mm_es<16><<<mt * 8 / 4, 256, 0, stream>>>(xsbuf, W2t, hbuf2, canon[7], canon[8], es, ed, n, 512, 64);
  k_mz<<<(n + 3) / 4, 256, 0, stream>>>(es, ed, rowA, colA, pbuf, zinv, n);
  k_gather16<<<n, 256, 0, stream>>>(hbuf2, pbuf, zinv, rowA, colA, canon[9], d_out, 0, n, flag);
  // ---- Layer 3 (t2s, C=64): x_t ----
  k_mm_es<64><<<mt * 32 / 4, 256, 0, stream>>>(xb, W3t, hbuf, canon[11], canon[12], es, ed, n, 2048, 128);
  k_mz<<<(n + 3) / 4, 256, 0, stream>>>(es, ed, rowB, colB, pbuf, zinv, n);
  k_gather64<<<n, 256, 0, stream>>>(hbuf, pbuf, zinv, rowB, colB, canon[13], xtbuf, n);
  // ---- Layer 4 (t2s, C=16): x_out -> out[1] ----
  k_mm_es<16><<<mt * 8 / 4, 256, 0, stream>>>(xtbuf, W4t, hbuf2, canon[15], canon[16], es, ed, n, 512, 64);
  k_mz<<<(n + 3) / 4, 256, 0, stream>>>(es, ed, rowB, colB, pbuf, zinv, n);
  k_gather16<<<n, 256, 0, stream>>>(hbuf2, pbuf, zinv, rowB, colB, canon[17], d_out, (size_t)n * 16, n, flag);
  // ---- Residual MLP: x_self -> out[2] ----
  k_residual<<<n / 16, 256, 0, stream>>>(xc,
      canon[18], canon[19], canon[20], canon[21], canon[22], canon[23],
      canon[24], canon[25], canon[26], canon[27], canon[28], canon[29],
      canon[30], canon[31], canon[32], canon[33], canon[34], canon[35],
      canon[36], canon[37],
      d_out, (size_t)2 * n * 16, n, flag);
}

// Round 4
// 458.758 us; speedup vs baseline: 2.8367x; 1.2566x over previous
//
#include <hip/hip_runtime.h>
#include <stdint.h>

// ---------- bf16 helpers (raw ushort representation) ----------
__device__ __forceinline__ float bf2f(unsigned short u) {
  union { unsigned int i; float f; } v; v.i = ((unsigned int)u) << 16; return v.f;
}
__device__ __forceinline__ unsigned short f2bf(float f) {
  union { float f; unsigned int i; } v; v.f = f;
  unsigned int i = v.i;
  unsigned int r = (i + 0x7fffu + ((i >> 16) & 1u)) >> 16;  // RNE
  return (unsigned short)r;
}

typedef __bf16 bf16x8 __attribute__((ext_vector_type(8)));
typedef float f32x4 __attribute__((ext_vector_type(4)));
union ABfrag { int4 i4; bf16x8 v; };

// Packed fragment layouts (lane = quad*16+mr):
//  A: Ap[((tm*KSTEPS + s)*64 + lane)*8 + j] = A[tm*16 + mr][s*32 + quad*8 + j]
//  B: Bp[((g*KSTEPS + s)*64 + lane)*8 + j] = W[s*32 + quad*8 + j][g*16 + mr]   (g = 16-col group)

// ---------- dtype detection (bf16-packed vs f32 inputs) ----------
__global__ __launch_bounds__(256) void k_detect(const unsigned int* __restrict__ x, int* flag) {
  __shared__ int cnt;
  if (threadIdx.x == 0) cnt = 0;
  __syncthreads();
  int c = 0;
  for (int i = threadIdx.x; i < 1024; i += 256) {
    unsigned int lo = x[i] & 0xFFFFu;
    int ex = (int)((lo >> 7) & 0xFF);
    if (ex >= 100 && ex <= 140) c++;
  }
  atomicAdd(&cnt, c);
  __syncthreads();
  if (threadIdx.x == 0) flag[0] = (cnt > 600) ? 1 : 0;  // 1 = bf16 inputs
}

// ---------- canonicalize small param tensors to f32 ----------
struct CanonDesc {
  const void* src[32];
  float* dst[32];
  int n[32];
  int cnt;
  int total;
};
__global__ __launch_bounds__(256) void k_canon(CanonDesc d, const int* __restrict__ flag) {
  int isbf = *flag;
  for (int idx = blockIdx.x * 256 + threadIdx.x; idx < d.total; idx += gridDim.x * 256) {
    int t = 0, off = idx;
    while (off >= d.n[t]) { off -= d.n[t]; ++t; }
    float v = isbf ? bf2f(((const unsigned short*)d.src[t])[off])
                   : ((const float*)d.src[t])[off];
    d.dst[t][off] = v;
  }
}

// ---------- x prep: raw -> f32 canon + packed-A bf16 (K=128) ----------
__global__ __launch_bounds__(256) void k_xprep(const void* __restrict__ x, float* __restrict__ xc,
                                               unsigned short* __restrict__ xp, int total,
                                               const int* __restrict__ flag) {
  int i = blockIdx.x * 256 + threadIdx.x;
  if (i >= total) return;
  int isbf = *flag;
  float v = isbf ? bf2f(((const unsigned short*)x)[i]) : ((const float*)x)[i];
  xc[i] = v;
  int row = i >> 7, c = i & 127;
  int tm = row >> 4, mr = row & 15;
  int s = c >> 5, quad = (c >> 3) & 3, j = c & 7;
  size_t idx = (((size_t)tm * 4 + s) * 64 + quad * 16 + mr) * 8 + j;
  xp[idx] = f2bf(v);
}

// ---------- weight pack: all 4 W's -> packed-B fragments, one launch ----------
__global__ __launch_bounds__(256) void k_wpack(const void* __restrict__ W1, const void* __restrict__ W2,
                                               const void* __restrict__ W3, const void* __restrict__ W4,
                                               unsigned short* __restrict__ P1, unsigned short* __restrict__ P2,
                                               unsigned short* __restrict__ P3, unsigned short* __restrict__ P4,
                                               const int* __restrict__ flag) {
  int u = blockIdx.x * 256 + threadIdx.x;   // 8-elem group index, 73728 total
  int isbf = *flag;
  const void* W; unsigned short* P; int K, N, lu;
  if (u < 32768)      { W = W1; P = P1; K = 128; N = 2048; lu = u; }
  else if (u < 36864) { W = W2; P = P2; K = 64;  N = 512;  lu = u - 32768; }
  else if (u < 69632) { W = W3; P = P3; K = 128; N = 2048; lu = u - 36864; }
  else                { W = W4; P = P4; K = 64;  N = 512;  lu = u - 69632; }
  int ksteps = K >> 5;
  int g = lu / (ksteps * 64);
  int rem = lu - g * (ksteps * 64);
  int s = rem >> 6, lane = rem & 63;
  int mr = lane & 15, quad = lane >> 4;
  int col = g * 16 + mr;
  int kbase = s * 32 + quad * 8;
#pragma unroll
  for (int j = 0; j < 8; ++j) {
    size_t src = (size_t)(kbase + j) * N + col;
    float v = isbf ? bf2f(((const unsigned short*)W)[src]) : ((const float*)W)[src];
    P[(size_t)lu * 8 + j] = f2bf(v);
  }
}

// ---------- CSR build ----------
__global__ __launch_bounds__(256) void k_deg_count(const int* __restrict__ ei, int* degA, int* degB, int E) {
  int e = blockIdx.x * 256 + threadIdx.x;
  if (e < E) { atomicAdd(&degA[ei[E + e]], 1); atomicAdd(&degB[ei[e]], 1); }
}
// exclusive scan of degA (block 0) / degB (block 1); adds +i for self-loops
__global__ __launch_bounds__(1024) void k_exscan2(const int* __restrict__ degA, const int* __restrict__ degB,
                                                  int* __restrict__ rowA, int* __restrict__ rowB, int n) {
  const int* deg = (blockIdx.x == 0) ? degA : degB;
  int* row = (blockIdx.x == 0) ? rowA : rowB;
  __shared__ int wsum[16], wbase[16];
  __shared__ int carry;
  if (threadIdx.x == 0) carry = 0;
  __syncthreads();
  int lane = threadIdx.x & 63, w = threadIdx.x >> 6;
  int chunks = (n + 1023) >> 10;
  for (int ch = 0; ch < chunks; ++ch) {
    int i = (ch << 10) + threadIdx.x;
    int v = (i < n) ? deg[i] : 0;
    int sc = v;
#pragma unroll
    for (int o = 1; o < 64; o <<= 1) { int t = __shfl_up(sc, o); if (lane >= o) sc += t; }
    if (lane == 63) wsum[w] = sc;
    __syncthreads();
    if (threadIdx.x < 16) {
      int v2 = wsum[threadIdx.x], s2 = v2;
#pragma unroll
      for (int o = 1; o < 16; o <<= 1) { int t = __shfl_up(s2, o); if (lane >= o) s2 += t; }
      wbase[threadIdx.x] = s2 - v2;
      if (threadIdx.x == 15) wsum[15] = s2;  // chunk total
    }
    __syncthreads();
    if (i < n) row[i] = carry + wbase[w] + (sc - v) + i;  // +i = self-loop slots
    __syncthreads();
    if (threadIdx.x == 0) carry += wsum[15];
    __syncthreads();
  }
  if (threadIdx.x == 0) row[n] = carry + n;
}
__global__ __launch_bounds__(256) void k_selfloop(const int* __restrict__ rowA, const int* __restrict__ rowB,
                                                 int* colA, int* colB, int* curA, int* curB, int n) {
  int i = blockIdx.x * 256 + threadIdx.x;
  if (i < n) {
    int ra = rowA[i]; colA[ra] = i; curA[i] = ra + 1;
    int rb = rowB[i]; colB[rb] = i; curB[i] = rb + 1;
  }
}
__global__ __launch_bounds__(256) void k_scatter(const int* __restrict__ ei, int* colA, int* colB,
                                                 int* curA, int* curB, int E) {
  int e = blockIdx.x * 256 + threadIdx.x;
  if (e < E) {
    int s = ei[e], d = ei[E + e];
    colA[atomicAdd(&curA[d], 1)] = s;
    colB[atomicAdd(&curB[s], 1)] = d;
  }
}

// ---------- bf16 MFMA matmul (packed A/B) + fused es/ed epilogue ----------
template<int CH, int KSTEPS>
__global__ __launch_bounds__(256) void k_mm_es(const unsigned short* __restrict__ Ap,
                                               const unsigned short* __restrict__ Bp,
                                               unsigned short* __restrict__ C,
                                               const float* __restrict__ a_s,
                                               const float* __restrict__ a_d,
                                               float* __restrict__ es, float* __restrict__ ed,
                                               int M, int N) {
  int wg = blockIdx.x * 4 + (threadIdx.x >> 6);
  int ntiles = N >> 6;
  int tm = wg / ntiles, tn = wg % ntiles;
  int lane = threadIdx.x & 63;
  int mr = lane & 15, quad = lane >> 4;
  const unsigned short* ap = Ap + ((size_t)tm * KSTEPS) * 512 + lane * 8;
  const unsigned short* bp = Bp + ((size_t)tn * 4 * KSTEPS) * 512 + lane * 8;
  f32x4 acc[4];
#pragma unroll
  for (int i = 0; i < 4; i++) acc[i] = (f32x4){0.f, 0.f, 0.f, 0.f};
#pragma unroll
  for (int s = 0; s < KSTEPS; ++s) {
    ABfrag a; a.i4 = *(const int4*)(ap + s * 512);
#pragma unroll
    for (int nt = 0; nt < 4; ++nt) {
      ABfrag b; b.i4 = *(const int4*)(bp + (size_t)(nt * KSTEPS + s) * 512);
      acc[nt] = __builtin_amdgcn_mfma_f32_16x16x32_bf16(a.v, b.v, acc[nt], 0, 0, 0);
    }
  }
#pragma unroll
  for (int nt = 0; nt < 4; ++nt)
#pragma unroll
    for (int r = 0; r < 4; ++r) {
      int row = tm * 16 + quad * 4 + r;
      int col = tn * 64 + nt * 16 + mr;
      C[(size_t)row * N + col] = f2bf(acc[nt][r]);
    }
  // ---- fused attention-logit epilogue ----
  if (CH == 64) {
    float pes[4] = {0.f,0.f,0.f,0.f}, ped[4] = {0.f,0.f,0.f,0.f};
    const float* asr = a_s + tn * 64;
    const float* adr = a_d + tn * 64;
#pragma unroll
    for (int nt = 0; nt < 4; ++nt) {
      float ws = asr[nt * 16 + mr], wd = adr[nt * 16 + mr];
#pragma unroll
      for (int r = 0; r < 4; ++r) { pes[r] += acc[nt][r] * ws; ped[r] += acc[nt][r] * wd; }
    }
#pragma unroll
    for (int m = 1; m < 16; m <<= 1)
#pragma unroll
      for (int r = 0; r < 4; ++r) {
        pes[r] += __shfl_xor(pes[r], m);
        ped[r] += __shfl_xor(ped[r], m);
      }
    if (mr == 0) {
#pragma unroll
      for (int r = 0; r < 4; ++r) {
        int row = tm * 16 + quad * 4 + r;
        es[row * 32 + tn] = pes[r];
        ed[row * 32 + tn] = ped[r];
      }
    }
  } else {
    float pes[4][4], ped[4][4];
#pragma unroll
    for (int nt = 0; nt < 4; ++nt) {
      float ws = a_s[(tn * 4 + nt) * 16 + mr];
      float wd = a_d[(tn * 4 + nt) * 16 + mr];
#pragma unroll
      for (int r = 0; r < 4; ++r) { pes[nt][r] = acc[nt][r] * ws; ped[nt][r] = acc[nt][r] * wd; }
    }
#pragma unroll
    for (int m = 1; m < 16; m <<= 1)
#pragma unroll
      for (int nt = 0; nt < 4; ++nt)
#pragma unroll
        for (int r = 0; r < 4; ++r) {
          pes[nt][r] += __shfl_xor(pes[nt][r], m);
          ped[nt][r] += __shfl_xor(ped[nt][r], m);
        }
    if (mr == 0) {
#pragma unroll
      for (int nt = 0; nt < 4; ++nt)
#pragma unroll
        for (int r = 0; r < 4; ++r) {
          int row = tm * 16 + quad * 4 + r;
          es[row * 32 + tn * 4 + nt] = pes[nt][r];
          ed[row * 32 + tn * 4 + nt] = ped[nt][r];
        }
    }
  }
}

// ---------- softmax M/Z + p per CSR slot: wave per node ----------
__global__ __launch_bounds__(256) void k_mz(const float* __restrict__ es, const float* __restrict__ ed,
                                            const int* __restrict__ rowp, const int* __restrict__ col,
                                            float* __restrict__ p, float* __restrict__ zinv, int n) {
  int wid = threadIdx.x >> 6, lane = threadIdx.x & 63;
  int i = blockIdx.x * 4 + wid;
  if (i >= n) return;
  int j2 = lane >> 5, h = lane & 31;
  int beg = rowp[i], end = rowp[i + 1];
  float edv = ed[i * 32 + h];
  float M = -1e30f;
  for (int j = beg + j2; j < end; j += 2) {
    float e = es[col[j] * 32 + h] + edv;
    e = (e > 0.f) ? e : 0.2f * e;
    M = fmaxf(M, e);
  }
  M = fmaxf(M, __shfl_xor(M, 32));
  float Z = 0.f;
  for (int j = beg + j2; j < end; j += 2) {
    float e = es[col[j] * 32 + h] + edv;
    e = (e > 0.f) ? e : 0.2f * e;
    float pj = __expf(e - M);
    p[(size_t)j * 32 + h] = pj;
    Z += pj;
  }
  Z += __shfl_xor(Z, 32);
  if (lane < 32) zinv[i * 32 + h] = 1.0f / Z;
}

// ---------- one-pass weighted gather, C=64; emits packed-A (K=64) output ----------
__global__ __launch_bounds__(256) void k_gather64(const unsigned short* __restrict__ h,
                                                  const float* __restrict__ p,
                                                  const float* __restrict__ zinv,
                                                  const int* __restrict__ rowp, const int* __restrict__ col,
                                                  const float* __restrict__ bias,
                                                  unsigned short* __restrict__ outp, int n) {
  int i = blockIdx.x;
  int wid = threadIdx.x >> 6, lane = threadIdx.x & 63;
  __shared__ float red[4][64];
  int beg = rowp[i], end = rowp[i + 1];
  int hbase = wid * 8;
  float acc[8] = {0.f,0.f,0.f,0.f,0.f,0.f,0.f,0.f};
  int j = beg;
  for (; j + 1 < end; j += 2) {
    int s0 = col[j], s1 = col[j + 1];
    const unsigned short* h0 = h + (size_t)s0 * 2048 + hbase * 64 + lane;
    const unsigned short* h1 = h + (size_t)s1 * 2048 + hbase * 64 + lane;
    const float* p0 = p + (size_t)j * 32 + hbase;
    const float* p1 = p + (size_t)(j + 1) * 32 + hbase;
#pragma unroll
    for (int q = 0; q < 8; ++q)
      acc[q] += p0[q] * bf2f(h0[q * 64]) + p1[q] * bf2f(h1[q * 64]);
  }
  if (j < end) {
    int s0 = col[j];
    const unsigned short* h0 = h + (size_t)s0 * 2048 + hbase * 64 + lane;
    const float* p0 = p + (size_t)j * 32 + hbase;
#pragma unroll
    for (int q = 0; q < 8; ++q)
      acc[q] += p0[q] * bf2f(h0[q * 64]);
  }
  float v = 0.f;
  const float* zi = zinv + i * 32 + hbase;
#pragma unroll
  for (int q = 0; q < 8; ++q) v += acc[q] * zi[q];
  red[wid][lane] = v;
  __syncthreads();
  if (threadIdx.x < 64) {
    int c = threadIdx.x;
    float t = red[0][c] + red[1][c] + red[2][c] + red[3][c];
    t = t * (1.f / 32.f) + bias[c];
    t = (t > 0.f) ? t : (__expf(t) - 1.f);  // elu
    // packed-A layout for the downstream K=64 GEMM
    int tm = i >> 4, mr = i & 15;
    int s = c >> 5, quad = (c >> 3) & 3, jj = c & 7;
    size_t idx = (((size_t)tm * 2 + s) * 64 + quad * 16 + mr) * 8 + jj;
    outp[idx] = f2bf(t);
  }
}

// ---------- one-pass weighted gather, C=16 (writes final output) ----------
__global__ __launch_bounds__(256) void k_gather16(const unsigned short* __restrict__ h,
                                                  const float* __restrict__ p,
                                                  const float* __restrict__ zinv,
                                                  const int* __restrict__ rowp, const int* __restrict__ col,
                                                  const float* __restrict__ bias,
                                                  void* __restrict__ outbase, size_t elem_off, int n,
                                                  const int* __restrict__ flag) {
  int i = blockIdx.x;
  int wid = threadIdx.x >> 6, lane = threadIdx.x & 63;
  int hq = lane >> 4, c = lane & 15;
  __shared__ float red[4][16];
  int beg = rowp[i], end = rowp[i + 1];
  float acc[2] = {0.f, 0.f};
  int j = beg;
  for (; j + 1 < end; j += 2) {
    int s0 = col[j], s1 = col[j + 1];
    const unsigned short* h0 = h + (size_t)s0 * 512;
    const unsigned short* h1 = h + (size_t)s1 * 512;
    const float* p0 = p + (size_t)j * 32;
    const float* p1 = p + (size_t)(j + 1) * 32;
#pragma unroll
    for (int q = 0; q < 2; ++q) {
      int hh = wid * 8 + q * 4 + hq;
      acc[q] += p0[hh] * bf2f(h0[hh * 16 + c]) + p1[hh] * bf2f(h1[hh * 16 + c]);
    }
  }
  if (j < end) {
    int s0 = col[j];
    const unsigned short* h0 = h + (size_t)s0 * 512;
    const float* p0 = p + (size_t)j * 32;
#pragma unroll
    for (int q = 0; q < 2; ++q) {
      int hh = wid * 8 + q * 4 + hq;
      acc[q] += p0[hh] * bf2f(h0[hh * 16 + c]);
    }
  }
  float v = acc[0] * zinv[i * 32 + wid * 8 + hq] + acc[1] * zinv[i * 32 + wid * 8 + 4 + hq];
  v += __shfl_xor(v, 16);
  v += __shfl_xor(v, 32);
  if (lane < 16) red[wid][c] = v;
  __syncthreads();
  if (threadIdx.x < 16) {
    float t = red[0][threadIdx.x] + red[1][threadIdx.x] + red[2][threadIdx.x] + red[3][threadIdx.x];
    t = t * (1.f / 32.f) + bias[threadIdx.x];
    t = (t > 0.f) ? t : (__expf(t) - 1.f);
    size_t o = elem_off + (size_t)i * 16 + threadIdx.x;
    if (*flag) ((unsigned short*)outbase)[o] = f2bf(t);
    else       ((float*)outbase)[o] = t;
  }
}

// ---------- fused residual network (f32) ----------
__global__ __launch_bounds__(256) void k_residual(const float* __restrict__ x,
    const float* __restrict__ rwa, const float* __restrict__ rba,
    const float* __restrict__ bn1g, const float* __restrict__ bn1b,
    const float* __restrict__ bn1m, const float* __restrict__ bn1v,
    const float* __restrict__ rwb, const float* __restrict__ rbb,
    const float* __restrict__ bn2g, const float* __restrict__ bn2b,
    const float* __restrict__ bn2m, const float* __restrict__ bn2v,
    const float* __restrict__ wsc, const float* __restrict__ bsc,
    const float* __restrict__ bnsg, const float* __restrict__ bnsb,
    const float* __restrict__ bnsm, const float* __restrict__ bnsv,
    const float* __restrict__ wfc, const float* __restrict__ bfc,
    void* __restrict__ outbase, size_t elem_off, int n, const int* __restrict__ flag) {
  __shared__ float xs[16][128];
  __shared__ float ha[16][16];
  __shared__ float tt[16][16];
  int nodebase = blockIdx.x * 16;
  for (int t = threadIdx.x; t < 16 * 128; t += 256)
    xs[t >> 7][t & 127] = x[(size_t)(nodebase + (t >> 7)) * 128 + (t & 127)];
  __syncthreads();
  int ni = threadIdx.x >> 4, c = threadIdx.x & 15;
  float ya = 0.f, ysc = 0.f;
  for (int k = 0; k < 128; ++k) {
    float xv = xs[ni][k];
    ya  += xv * rwa[k * 16 + c];
    ysc += xv * wsc[k * 16 + c];
  }
  ya += rba[c]; ysc += bsc[c];
  float s1 = bn1g[c] * rsqrtf(bn1v[c] + 1e-5f);
  ya = (ya - bn1m[c]) * s1 + bn1b[c];
  ya = fmaxf(ya, 0.f);
  float ss = bnsg[c] * rsqrtf(bnsv[c] + 1e-5f);
  ysc = (ysc - bnsm[c]) * ss + bnsb[c];
  ha[ni][c] = ya;
  __syncthreads();
  float h2 = rbb[c];
  for (int k = 0; k < 16; ++k) h2 += ha[ni][k] * rwb[k * 16 + c];
  float s2 = bn2g[c] * rsqrtf(bn2v[c] + 1e-5f);
  h2 = (h2 - bn2m[c]) * s2 + bn2b[c];
  tt[ni][c] = fmaxf(h2 + ysc, 0.f);
  __syncthreads();
  float o = bfc[c];
  for (int k = 0; k < 16; ++k) o += tt[ni][k] * wfc[k * 16 + c];
  size_t oo = elem_off + (size_t)(nodebase + ni) * 16 + c;
  if (*flag) ((unsigned short*)outbase)[oo] = f2bf(o);
  else       ((float*)outbase)[oo] = o;
}

extern "C" void kernel_launch(void* const* d_in, const int* in_sizes, int n_in,
                              void* d_out, int out_size, void* d_ws, size_t ws_size,
                              hipStream_t stream) {
  const int n = in_sizes[0] / 128;   // 10000
  const int E = in_sizes[1] / 2;     // 80000
  const int* ei = (const int*)d_in[1];

  char* wsp = (char*)d_ws; size_t off = 0;
  auto alloc = [&](size_t bytes) -> void* {
    void* p = wsp + off; off = (off + bytes + 255) & ~(size_t)255; return p;
  };
  int* flag = (int*)alloc(4);
  float* xc = (float*)alloc((size_t)n * 128 * 4);
  unsigned short* xp = (unsigned short*)alloc((size_t)n * 128 * 2);   // packed A, K=128
  unsigned short* W1p = (unsigned short*)alloc((size_t)2048 * 128 * 2);
  unsigned short* W2p = (unsigned short*)alloc((size_t)512 * 64 * 2);
  unsigned short* W3p = (unsigned short*)alloc((size_t)2048 * 128 * 2);
  unsigned short* W4p = (unsigned short*)alloc((size_t)512 * 64 * 2);
  unsigned short* hbuf = (unsigned short*)alloc((size_t)n * 2048 * 2);
  unsigned short* hbuf2 = hbuf;  // reuse (lifetimes disjoint)
  float* es = (float*)alloc((size_t)n * 32 * 4);
  float* ed = (float*)alloc((size_t)n * 32 * 4);
  float* pbuf = (float*)alloc((size_t)(E + n) * 32 * 4);
  float* zinv = (float*)alloc((size_t)n * 32 * 4);
  unsigned short* xsp = (unsigned short*)alloc((size_t)n * 64 * 2);   // packed A, K=64
  unsigned short* xtp = (unsigned short*)alloc((size_t)n * 64 * 2);
  int* rowA = (int*)alloc((size_t)(n + 1) * 4);
  int* rowB = (int*)alloc((size_t)(n + 1) * 4);
  int* colA = (int*)alloc((size_t)(E + n) * 4);
  int* colB = (int*)alloc((size_t)(E + n) * 4);
  int* degAB = (int*)alloc((size_t)2 * n * 4);
  int* degA = degAB, * degB = degAB + n;
  int* curA = (int*)alloc((size_t)n * 4);
  int* curB = (int*)alloc((size_t)n * 4);

  static const int cidx[32] = {3,4,5, 7,8,9, 11,12,13, 15,16,17,
                               18,19,20,21,22,23,24,25,26,27,28,29,
                               30,31,32,33,34,35,36,37};
  CanonDesc cd; cd.cnt = 32; cd.total = 0;
  float* canon[38] = {nullptr};
  for (int t = 0; t < 32; ++t) {
    int ii = cidx[t];
    canon[ii] = (float*)alloc((size_t)in_sizes[ii] * 4);
    cd.src[t] = d_in[ii];
    cd.dst[t] = canon[ii];
    cd.n[t] = in_sizes[ii];
    cd.total += in_sizes[ii];
  }
  (void)ws_size; (void)n_in; (void)out_size;

  // ---- dtype detect + canonicalize + packs ----
  k_detect<<<1, 256, 0, stream>>>((const unsigned int*)d_in[0], flag);
  k_canon<<<64, 256, 0, stream>>>(cd, flag);
  k_xprep<<<(n * 128) / 256, 256, 0, stream>>>(d_in[0], xc, xp, n * 128, flag);
  k_wpack<<<288, 256, 0, stream>>>(d_in[2], d_in[6], d_in[10], d_in[14],
                                   W1p, W2p, W3p, W4p, flag);

  // ---- CSR build (both flows) ----
  hipMemsetAsync(degAB, 0, (size_t)2 * n * 4, stream);
  k_deg_count<<<(E + 255) / 256, 256, 0, stream>>>(ei, degA, degB, E);
  k_exscan2<<<2, 1024, 0, stream>>>(degA, degB, rowA, rowB, n);
  k_selfloop<<<(n + 255) / 256, 256, 0, stream>>>(rowA, rowB, colA, colB, curA, curB, n);
  k_scatter<<<(E + 255) / 256, 256, 0, stream>>>(ei, colA, colB, curA, curB, E);

  const int mt = n / 16;  // 625
  // ---- Layer 1 (s2t, C=64): x_s ----
  k_mm_es<64,4><<<mt * 32 / 4, 256, 0, stream>>>(xp, W1p, hbuf, canon[3], canon[4], es, ed, n, 2048);
  k_mz<<<(n + 3) / 4, 256, 0, stream>>>(es, ed, rowA, colA, pbuf, zinv, n);
  k_gather64<<<n, 256, 0, stream>>>(hbuf, pbuf, zinv, rowA, colA, canon[5], xsp, n);
  // ---- Layer 2 (s2t, C=16): x_in -> out[0] ----
  k_mm_es<16,2><<<mt * 8 / 4, 256, 0, stream>>>(xsp, W2p, hbuf2, canon[7], canon[8], es, ed, n, 512);
  k_mz<<<(n + 3) / 4, 256, 0, stream>>>(es, ed, rowA, colA, pbuf, zinv, n);
  k_gather16<<<n, 256, 0, stream>>>(hbuf2, pbuf, zinv, rowA, colA, canon[9], d_out, 0, n, flag);
  // ---- Layer 3 (t2s, C=64): x_t ----
  k_mm_es<64,4><<<mt * 32 / 4, 256, 0, stream>>>(xp, W3p, hbuf, canon[11], canon[12], es, ed, n, 2048);
  k_mz<<<(n + 3) / 4, 256, 0, stream>>>(es, ed, rowB, colB, pbuf, zinv, n);
  k_gather64<<<n, 256, 0, stream>>>(hbuf, pbuf, zinv, rowB, colB, canon[13], xtp, n);
  // ---- Layer 4 (t2s, C=16): x_out -> out[1] ----
  k_mm_es<16,2><<<mt * 8 / 4, 256, 0, stream>>>(xtp, W4p, hbuf2, canon[15], canon[16], es, ed, n, 512);
  k_mz<<<(n + 3) / 4, 256, 0, stream>>>(es, ed, rowB, colB, pbuf, zinv, n);
  k_gather16<<<n, 256, 0, stream>>>(hbuf2, pbuf, zinv, rowB, colB, canon[17], d_out, (size_t)n * 16, n, flag);
  // ---- Residual MLP: x_self -> out[2] ----
  k_residual<<<n / 16, 256, 0, stream>>>(xc,
      canon[18], canon[19], canon[20], canon[21], canon[22], canon[23],
      canon[24], canon[25], canon[26], canon[27], canon[28], canon[29],
      canon[30], canon[31], canon[32], canon[33], canon[34], canon[35],
      canon[36], canon[37],
      d_out, (size_t)2 * n * 16, n, flag);
}